// Round 19
// baseline (642.289 us; speedup 1.0000x reference)
//
#include <hip/hip_runtime.h>
#include <hip/hip_bf16.h>
#include <hip/hip_cooperative_groups.h>

namespace cg = cooperative_groups;

#define NL 3
#define HD 64
#define TCAP 1024
#define NB 8

typedef unsigned char u8;

__device__ __forceinline__ float sigf(float x){ return 1.f/(1.f+__expf(-x)); }

__device__ __forceinline__ float wsum(float v){
  #pragma unroll
  for (int off=32; off; off>>=1) v += __shfl_xor(v, off, 64);
  return v;
}

__device__ __forceinline__ float bcastf(float v, int l){
  return __int_as_float(__builtin_amdgcn_readlane(__float_as_int(v), l));
}

__device__ __forceinline__ float ldin(const void* p, size_t i, int bf){
  return bf ? __bfloat162float(((const __hip_bfloat16*)p)[i]) : ((const float*)p)[i];
}

__device__ __forceinline__ bool testbit(const unsigned* __restrict__ w, int n){
  return (w[n>>5] >> (n&31)) & 1u;
}

// per-wave dtype probe: bf16 halves of N(0,0.05) data have sane exponents
__device__ __forceinline__ int probe_bf(const void* probe, int lane){
  unsigned short h = ((const unsigned short*)probe)[lane];
  int e = (h >> 7) & 0xFF;
  int sane = ((h & 0x7FFF) == 0) || (e >= 96 && e <= 132);
  unsigned long long m = __ballot(sane != 0);
  return (__popcll(m) >= 56) ? 1 : 0;
}

// -------- ONE setup kernel: weight convert/transpose + attn tables + query-node init --------
__global__ void __launch_bounds__(256) k_setup(
    const void* __restrict__ W_h, const void* __restrict__ Ws,
    const void* __restrict__ Wih, const void* __restrict__ Whh,
    const void* __restrict__ bih, const void* __restrict__ bhh,
    const void* __restrict__ wal, const void* __restrict__ bal,
    const void* __restrict__ Wf,  const void* __restrict__ rel,
    const void* __restrict__ Wr,  const void* __restrict__ Wqr,
    const void* __restrict__ bqr, const void* __restrict__ qre,
    const int* __restrict__ q_rel, const int* __restrict__ qsub,
    float* __restrict__ WhF, float* __restrict__ WsF,
    float* __restrict__ WiT, float* __restrict__ WhT,
    float* __restrict__ biF, float* __restrict__ bhF,
    float* __restrict__ waF, float* __restrict__ baF,
    float* __restrict__ WfF, float* __restrict__ REL,
    float* __restrict__ R2, float* __restrict__ QR,
    float* __restrict__ hid, float* __restrict__ HS2, unsigned* __restrict__ liveW,
    int* __restrict__ stamp, int* __restrict__ plist, int* __restrict__ pcnt,
    int NR, int B, int PB, int TB)
{
  int lane = threadIdx.x & 63;
  int bf = probe_bf(rel, lane);

  if ((int)blockIdx.x < PB){
    int j = blockIdx.x*256 + threadIdx.x;
    const int sWT = NL*HD*HD, sWI = NL*192*HD, sB = NL*192;
    if (j < sWT){ WhF[j]=ldin(W_h,j,bf); return; } j-=sWT;
    if (j < sWT){ WsF[j]=ldin(Ws ,j,bf); return; } j-=sWT;
    if (j < sWI){ int l=j/(192*HD), q=j%(192*HD), h=q/192, a=q%192;
                  WiT[j]=ldin(Wih,(size_t)l*192*HD + (size_t)a*HD + h,bf); return; } j-=sWI;
    if (j < sWI){ int l=j/(192*HD), q=j%(192*HD), h=q/192, a=q%192;
                  WhT[j]=ldin(Whh,(size_t)l*192*HD + (size_t)a*HD + h,bf); return; } j-=sWI;
    if (j < sB){ biF[j]=ldin(bih,j,bf); return; } j-=sB;
    if (j < sB){ bhF[j]=ldin(bhh,j,bf); return; } j-=sB;
    if (j < NL*HD){ waF[j]=ldin(wal,j,bf); return; } j-=NL*HD;
    if (j < NL){ baF[j]=ldin(bal,j,bf); return; } j-=NL;
    if (j < HD){ WfF[j]=ldin(Wf,j,bf); return; } j-=HD;
    if (j < NL*NR*HD){ REL[j]=ldin(rel,j,bf); return; }
    return;
  }
  if ((int)blockIdx.x < PB+TB){
    int bid = ((int)blockIdx.x - PB)*4 + (threadIdx.x>>6);
    if (bid < NL*NR){
      int l = bid/NR, r = bid%NR;
      float x = ldin(rel,(size_t)(l*NR+r)*HD + lane,bf);
      float acc = 0.f;
      #pragma unroll
      for (int h=0; h<HD; ++h)
        acc = fmaf(bcastf(x, h), ldin(Wr,(size_t)(l*HD+h)*HD + lane,bf), acc);
      R2[(size_t)bid*HD + lane] = acc;
    } else if (bid < NL*NR + NL*B){
      int b2 = bid - NL*NR;
      int l = b2/B, b = b2%B;
      int r = q_rel[b];
      float x = ldin(rel,(size_t)(l*NR+r)*HD + lane,bf);
      float acc = ldin(bqr,(size_t)l*HD + lane,bf);
      #pragma unroll
      for (int h=0; h<HD; ++h)
        acc = fmaf(bcastf(x, h), ldin(Wqr,(size_t)(l*HD+h)*HD + lane,bf), acc);
      QR[(size_t)b2*HD + lane] = acc;
    }
    return;
  }
  int b = ((int)blockIdx.x - PB - TB)*4 + (threadIdx.x>>6);
  if (b >= B) return;
  int n = qsub[b];
  for (int b2 = b+1; b2 < B; ++b2) if (qsub[b2] == n) return;  // last dup wins
  int r = q_rel[b];
  float v = ldin(qre,(size_t)r*HD + lane,bf);
  hid[(size_t)n*HD + lane] = v;
  float acc = 0.f;
  #pragma unroll 8
  for (int h=0; h<HD; ++h)
    acc = fmaf(bcastf(v,h), ldin(Ws,(size_t)h*HD + lane,bf), acc);  // Ws layer 0 raw [h][a]
  HS2[(size_t)n*HD + lane] = acc;
  if (lane==0){
    atomicOr(&liveW[n>>5], 1u<<(n&31));
    stamp[n] = 1;
    int idx = atomicAdd(pcnt, 1);
    plist[idx] = n;
  }
}

// -------- parameters for the fused cooperative kernel --------
struct KP {
  const int *sub, *rel_i, *obj, *eb;
  float *agg, *hid, *HS2;
  unsigned *liveW;
  int *stamp, *cnts, *listA, *listB;
  const float *R2, *QR, *REL;
  const float *WhF, *WsF, *WiT, *WhT, *biF, *bhF, *waF, *baF, *WfF;
  float *out;
  int E, N, NR, B;
};

// -------- ONE cooperative kernel: [edge -> sync -> node+died -> sync] x 3 layers --------
__global__ void __launch_bounds__(256, 4) k_main(KP p)
{
  cg::grid_group grid = cg::this_grid();
  __shared__ int s_cnt;
  __shared__ int s_base;
  __shared__ int s_buf[TCAP];

  int lane = threadIdx.x & 63;
  int wid = (blockIdx.x*256 + threadIdx.x) >> 6;
  int nw = gridDim.x*4;

  int* prevL = p.listA;            // live list entering current layer
  const int* prevCnt = p.cnts + 3;
  int* curT = p.listB;             // touched list being built this layer

  for (int l = 0; l < NL; ++l){
    int ep = l + 2;
    const float* __restrict__ R2l  = p.R2  + (size_t)l*p.NR*HD;
    const float* __restrict__ QRl  = p.QR  + (size_t)l*p.B*HD;
    const float* __restrict__ RELl = p.REL + (size_t)l*p.NR*HD;
    int* tcnt = p.cnts + 4 + l;

    // ================= edge phase =================
    if (threadIdx.x == 0) s_cnt = 0;
    __syncthreads();
    {
      float wa = p.waF[l*HD + lane];
      float ba = p.baF[l];
      long long stride = (long long)nw*256;
      long long base0 = (long long)wid*256;
      int4 s4 = make_int4(0,0,0,0);
      if (base0 + 256 <= p.E)
        s4 = *reinterpret_cast<const int4*>(&p.sub[base0 + 4*(long long)lane]);

      for (long long base = base0; base < p.E; base += stride){
        bool vec = (base + 256 <= p.E);
        long long nbase = base + stride;
        int4 s4n = make_int4(0,0,0,0);
        if (nbase < p.E && nbase + 256 <= p.E)
          s4n = *reinterpret_cast<const int4*>(&p.sub[nbase + 4*(long long)lane]);

        unsigned long long m[4];
        if (vec){
          m[0] = __ballot(testbit(p.liveW, s4.x));
          m[1] = __ballot(testbit(p.liveW, s4.y));
          m[2] = __ballot(testbit(p.liveW, s4.z));
          m[3] = __ballot(testbit(p.liveW, s4.w));
        } else {
          #pragma unroll
          for (int j=0;j<4;++j){
            long long e = base + 4*(long long)lane + j;
            bool lv = (e < p.E) && testbit(p.liveW, p.sub[e]);
            m[j] = __ballot(lv);
          }
        }
        #pragma unroll
        for (int j=0;j<4;++j){
          unsigned long long mask = m[j];
          while (mask){
            int bit = (int)__ffsll(mask) - 1;
            mask &= mask - 1;
            long long ee = base + 4*(long long)bit + j;
            int ss = p.sub[ee], r = p.rel_i[ee], o = p.obj[ee], b = p.eb[ee];
            float hs  = p.hid[(size_t)ss*HD + lane];
            float pre = p.HS2[(size_t)ss*HD + lane] + R2l[(size_t)r*HD + lane] + QRl[(size_t)b*HD + lane];
            pre = fmaxf(pre, 0.f);
            float alpha = sigf(wsum(pre*wa) + ba);
            unsafeAtomicAdd(&p.agg[(size_t)o*HD + lane], alpha * hs * RELl[(size_t)r*HD + lane]);
            if (lane==0){
              int old = atomicExch(&p.stamp[o], ep);
              if (old != ep){
                int li = atomicAdd(&s_cnt, 1);
                if (li < TCAP) s_buf[li] = o;
                else { int gi = atomicAdd(tcnt, 1); curT[gi] = o; }
              }
            }
          }
        }
        s4 = s4n;
      }
    }
    __syncthreads();
    {
      int cnt = s_cnt; if (cnt > TCAP) cnt = TCAP;
      if (threadIdx.x == 0 && cnt > 0) s_base = atomicAdd(tcnt, cnt);
      __syncthreads();
      if (cnt > 0){
        int b0 = s_base;
        for (int i = threadIdx.x; i < cnt; i += 256) curT[b0 + i] = s_buf[i];
      }
    }
    grid.sync();

    // ================= node phase =================
    {
      int cntv = tcnt[0]; if (cntv > p.N) cntv = p.N;
      int isFirst = (l==0), isLast = (l==NL-1);
      const float* __restrict__ WhFl = p.WhF + (size_t)l*HD*HD;
      const float* __restrict__ WiTl = p.WiT + (size_t)l*192*HD;
      const float* __restrict__ WhTl = p.WhT + (size_t)l*192*HD;
      const float* __restrict__ biFl = p.biF + l*192;
      const float* __restrict__ bhFl = p.bhF + l*192;
      const float* __restrict__ WsFn = (l < NL-1) ? (p.WsF + (size_t)(l+1)*HD*HD) : p.WsF;
      float bi0=biFl[lane], bi1=biFl[HD+lane], bi2=biFl[2*HD+lane];
      float bh0=bhFl[lane], bh1=bhFl[HD+lane], bh2=bhFl[2*HD+lane];
      float wfv = isLast ? p.WfF[lane] : 0.f;

      for (int i0 = wid*NB; i0 < cntv; i0 += nw*NB){
        int nd[NB]; bool val[NB]; bool wp[NB]; float av[NB];
        #pragma unroll
        for (int j=0;j<NB;++j){
          val[j] = (i0+j) < cntv;
          nd[j]  = curT[val[j] ? (i0+j) : i0];
          wp[j]  = (!isFirst) && val[j] && testbit(p.liveW, nd[j]);  // read BEFORE overwrite
          av[j]  = val[j] ? p.agg[(size_t)nd[j]*HD + lane] : 0.f;
        }
        if (!isLast){
          #pragma unroll
          for (int j=0;j<NB;++j) if (val[j]) p.agg[(size_t)nd[j]*HD + lane] = 0.f;
        }

        float hm[NB];
        #pragma unroll
        for (int j=0;j<NB;++j) hm[j] = 0.f;
        #pragma unroll 8
        for (int h=0; h<HD; ++h){
          float w = WhFl[h*HD + lane];
          #pragma unroll
          for (int j=0;j<NB;++j) hm[j] = fmaf(bcastf(av[j],h), w, hm[j]);
        }
        float mask[NB]; float h0v[NB];
        #pragma unroll
        for (int j=0;j<NB;++j){
          hm[j] = fmaxf(hm[j], 0.f);
          mask[j] = (__ballot(hm[j] != 0.f) != 0ull) ? 1.f : 0.f;
          h0v[j] = wp[j] ? p.hid[(size_t)nd[j]*HD + lane] : 0.f;    // wp wave-uniform
        }

        float gi0[NB], gi1[NB], gi2[NB], gh0[NB], gh1[NB], gh2[NB];
        #pragma unroll
        for (int j=0;j<NB;++j){ gi0[j]=bi0; gi1[j]=bi1; gi2[j]=bi2; gh0[j]=bh0; gh1[j]=bh1; gh2[j]=bh2; }
        #pragma unroll 4
        for (int h=0; h<HD; ++h){
          const float* __restrict__ wr = WiTl + (size_t)h*192;
          float w0 = wr[lane], w1 = wr[64+lane], w2 = wr[128+lane];
          #pragma unroll
          for (int j=0;j<NB;++j){
            float x = bcastf(hm[j],h);
            gi0[j] = fmaf(x, w0, gi0[j]);
            gi1[j] = fmaf(x, w1, gi1[j]);
            gi2[j] = fmaf(x, w2, gi2[j]);
          }
        }
        #pragma unroll
        for (int j=0;j<NB;++j){
          if (wp[j]){
            #pragma unroll 4
            for (int h=0; h<HD; ++h){
              const float* __restrict__ wr = WhTl + (size_t)h*192;
              float y = bcastf(h0v[j],h);
              gh0[j] = fmaf(y, wr[lane],     gh0[j]);
              gh1[j] = fmaf(y, wr[64+lane],  gh1[j]);
              gh2[j] = fmaf(y, wr[128+lane], gh2[j]);
            }
          }
        }

        float hn[NB];
        #pragma unroll
        for (int j=0;j<NB;++j){
          float r = sigf(gi0[j]+gh0[j]);
          float z = sigf(gi1[j]+gh1[j]);
          float nn = tanhf(gi2[j] + r*gh2[j]);
          hn[j] = ((1.f - z)*nn + z*h0v[j])*mask[j];
        }

        if (isLast){
          #pragma unroll
          for (int j=0;j<NB;++j){
            float sc = wsum(hn[j] * wfv);
            if (lane==0 && val[j]) p.out[nd[j]] = sc;
          }
          continue;
        }
        #pragma unroll
        for (int j=0;j<NB;++j){
          unsigned long long lv = __ballot(hn[j] != 0.f);
          if (val[j]){
            p.hid[(size_t)nd[j]*HD + lane] = hn[j];
            if (lane==0){
              unsigned bit = 1u << (nd[j]&31);
              if (lv) atomicOr (&p.liveW[nd[j]>>5],  bit);
              else    atomicAnd(&p.liveW[nd[j]>>5], ~bit);
            }
          }
        }

        float acc[NB];
        #pragma unroll
        for (int j=0;j<NB;++j) acc[j] = 0.f;
        #pragma unroll 8
        for (int h=0; h<HD; ++h){
          float w = WsFn[h*HD + lane];
          #pragma unroll
          for (int j=0;j<NB;++j) acc[j] = fmaf(bcastf(hn[j],h), w, acc[j]);
        }
        #pragma unroll
        for (int j=0;j<NB;++j) if (val[j]) p.HS2[(size_t)nd[j]*HD + lane] = acc[j];
      }

      // folded died-clear: prev-live nodes that got no messages this layer
      if (!isLast){
        int pc = prevCnt[0]; if (pc > p.N) pc = p.N;
        for (int i = blockIdx.x*256 + threadIdx.x; i < pc; i += gridDim.x*256){
          int n = prevL[i];
          if (p.stamp[n] != ep) atomicAnd(&p.liveW[n>>5], ~(1u<<(n&31)));
        }
      }
    }
    grid.sync();

    prevL = curT;
    prevCnt = tcnt;
    curT = (curT == p.listB) ? p.listA : p.listB;
  }
}

extern "C" void kernel_launch(void* const* d_in, const int* in_sizes, int n_in,
                              void* d_out, int out_size, void* d_ws, size_t ws_size,
                              hipStream_t stream)
{
  const int* sub   = (const int*)d_in[0];
  const int* rel_i = (const int*)d_in[1];
  const int* obj   = (const int*)d_in[2];
  const int* eb    = (const int*)d_in[3];
  const int* q_rel = (const int*)d_in[4];
  const int* qsub  = (const int*)d_in[5];
  const void* rela = d_in[6];
  const void* qre  = d_in[7];
  const void* Wsp  = d_in[8];
  const void* Wr   = d_in[9];
  const void* Wqr  = d_in[10];
  const void* bqr  = d_in[11];
  const void* wal  = d_in[12];
  const void* bal  = d_in[13];
  const void* W_h  = d_in[14];
  const void* Wih  = d_in[15];
  const void* Whh  = d_in[16];
  const void* bih  = d_in[17];
  const void* bhh  = d_in[18];
  const void* Wf   = d_in[19];

  int E  = in_sizes[0];
  int B  = in_sizes[4];
  int NR = in_sizes[6]/(NL*HD);
  int N  = out_size;
  int NW = (N + 31) / 32;

  float* ws = (float*)d_ws;
  size_t o = 0;
  float* agg  = ws + o; o += (size_t)N*HD;     // ┐ ONE memset region:
  int*   stamp= (int*)(ws + o); o += N;        // │ agg + stamp + cnts + liveW
  int*   cnts = (int*)(ws + o); o += 16;       // │
  unsigned* liveW = (unsigned*)(ws + o); o += NW;  // ┘ 12.5 KB bitmask
  float* hid  = ws + o; o += (size_t)N*HD;
  float* HS2  = ws + o; o += (size_t)N*HD;
  float* R2   = ws + o; o += (size_t)NL*NR*HD;
  float* QR   = ws + o; o += (size_t)NL*B*HD;
  float* REL  = ws + o; o += (size_t)NL*NR*HD;
  float* WhF  = ws + o; o += NL*HD*HD;
  float* WsF  = ws + o; o += NL*HD*HD;
  float* WiT  = ws + o; o += NL*192*HD;
  float* WhT  = ws + o; o += NL*192*HD;
  float* biF  = ws + o; o += NL*192;
  float* bhF  = ws + o; o += NL*192;
  float* waF  = ws + o; o += NL*HD;
  float* baF  = ws + o; o += NL;
  float* WfF  = ws + o; o += HD;
  int*   listA= (int*)(ws + o); o += N;
  int*   listB= (int*)(ws + o); o += N;

  // cnts: [3]=init live cnt, [4..6]=touched cnts
  size_t z1 = (size_t)N*HD*sizeof(float) + (size_t)N*sizeof(int)
            + 16*sizeof(int) + (size_t)NW*sizeof(unsigned);
  hipMemsetAsync(agg, 0, z1, stream);
  hipMemsetAsync(d_out, 0, (size_t)N*sizeof(float), stream);

  int prepN = 2*(NL*HD*HD) + 2*(NL*192*HD) + 2*(NL*192) + NL*HD + NL + HD + NL*NR*HD;
  int PB = (prepN + 255)/256;
  int TB = (NL*NR + NL*B + 3)/4;
  int IB = (B + 3)/4;
  k_setup<<<PB + TB + IB, 256, 0, stream>>>(
      W_h, Wsp, Wih, Whh, bih, bhh, wal, bal, Wf, rela, Wr, Wqr, bqr, qre,
      q_rel, qsub,
      WhF, WsF, WiT, WhT, biF, bhF, waF, baF, WfF, REL, R2, QR,
      hid, HS2, liveW, stamp, listA, cnts+3, NR, B, PB, TB);

  KP kp;
  kp.sub = sub; kp.rel_i = rel_i; kp.obj = obj; kp.eb = eb;
  kp.agg = agg; kp.hid = hid; kp.HS2 = HS2;
  kp.liveW = liveW; kp.stamp = stamp; kp.cnts = cnts;
  kp.listA = listA; kp.listB = listB;
  kp.R2 = R2; kp.QR = QR; kp.REL = REL;
  kp.WhF = WhF; kp.WsF = WsF; kp.WiT = WiT; kp.WhT = WhT;
  kp.biF = biF; kp.bhF = bhF; kp.waF = waF; kp.baF = baF; kp.WfF = WfF;
  kp.out = (float*)d_out;
  kp.E = E; kp.N = N; kp.NR = NR; kp.B = B;

  int grid = 960;                       // <= 4 blocks/CU x 256 CUs (launch_bounds(256,4))
  int maxb = 0;
  if (hipOccupancyMaxActiveBlocksPerMultiprocessor(&maxb, k_main, 256, 0) == hipSuccess
      && maxb > 0){
    int cap = maxb * 256;               // MI355X: 256 CUs
    if (grid > cap) grid = cap;
  }
  void* args[] = { &kp };
  hipLaunchCooperativeKernel((const void*)k_main, dim3(grid), dim3(256), args, 0, stream);
}

// Round 20
// 172.524 us; speedup vs baseline: 3.7229x; 3.7229x over previous
//
#include <hip/hip_runtime.h>
#include <hip/hip_bf16.h>

#define NL 3
#define HD 64
#define TCAP 1024
#define NB 8

typedef unsigned char u8;

__device__ __forceinline__ float sigf(float x){ return 1.f/(1.f+__expf(-x)); }

__device__ __forceinline__ float wsum(float v){
  #pragma unroll
  for (int off=32; off; off>>=1) v += __shfl_xor(v, off, 64);
  return v;
}

__device__ __forceinline__ float bcastf(float v, int l){
  return __int_as_float(__builtin_amdgcn_readlane(__float_as_int(v), l));
}

__device__ __forceinline__ float ldin(const void* p, size_t i, int bf){
  return bf ? __bfloat162float(((const __hip_bfloat16*)p)[i]) : ((const float*)p)[i];
}

__device__ __forceinline__ bool testbit(const unsigned* __restrict__ w, int n){
  return (w[n>>5] >> (n&31)) & 1u;
}

// per-wave dtype probe: bf16 halves of N(0,0.05) data have sane exponents
__device__ __forceinline__ int probe_bf(const void* probe, int lane){
  unsigned short h = ((const unsigned short*)probe)[lane];
  int e = (h >> 7) & 0xFF;
  int sane = ((h & 0x7FFF) == 0) || (e >= 96 && e <= 132);
  unsigned long long m = __ballot(sane != 0);
  return (__popcll(m) >= 56) ? 1 : 0;
}

// -------- ONE setup kernel: weight convert/transpose + attn tables + query-node init --------
__global__ void __launch_bounds__(256) k_setup(
    const void* __restrict__ W_h, const void* __restrict__ Ws,
    const void* __restrict__ Wih, const void* __restrict__ Whh,
    const void* __restrict__ bih, const void* __restrict__ bhh,
    const void* __restrict__ wal, const void* __restrict__ bal,
    const void* __restrict__ Wf,  const void* __restrict__ rel,
    const void* __restrict__ Wr,  const void* __restrict__ Wqr,
    const void* __restrict__ bqr, const void* __restrict__ qre,
    const int* __restrict__ q_rel, const int* __restrict__ qsub,
    float* __restrict__ WhF, float* __restrict__ WsF,
    float* __restrict__ WiT, float* __restrict__ WhT,
    float* __restrict__ biF, float* __restrict__ bhF,
    float* __restrict__ waF, float* __restrict__ baF,
    float* __restrict__ WfF, float* __restrict__ REL,
    float* __restrict__ R2, float* __restrict__ QR,
    float* __restrict__ hid, float* __restrict__ HS2, unsigned* __restrict__ liveW,
    int* __restrict__ stamp, int* __restrict__ plist, int* __restrict__ pcnt,
    int NR, int B, int PB, int TB)
{
  int lane = threadIdx.x & 63;
  int bf = probe_bf(rel, lane);

  if ((int)blockIdx.x < PB){
    int j = blockIdx.x*256 + threadIdx.x;
    const int sWT = NL*HD*HD, sWI = NL*192*HD, sB = NL*192;
    if (j < sWT){ WhF[j]=ldin(W_h,j,bf); return; } j-=sWT;
    if (j < sWT){ WsF[j]=ldin(Ws ,j,bf); return; } j-=sWT;
    if (j < sWI){ int l=j/(192*HD), q=j%(192*HD), h=q/192, a=q%192;
                  WiT[j]=ldin(Wih,(size_t)l*192*HD + (size_t)a*HD + h,bf); return; } j-=sWI;
    if (j < sWI){ int l=j/(192*HD), q=j%(192*HD), h=q/192, a=q%192;
                  WhT[j]=ldin(Whh,(size_t)l*192*HD + (size_t)a*HD + h,bf); return; } j-=sWI;
    if (j < sB){ biF[j]=ldin(bih,j,bf); return; } j-=sB;
    if (j < sB){ bhF[j]=ldin(bhh,j,bf); return; } j-=sB;
    if (j < NL*HD){ waF[j]=ldin(wal,j,bf); return; } j-=NL*HD;
    if (j < NL){ baF[j]=ldin(bal,j,bf); return; } j-=NL;
    if (j < HD){ WfF[j]=ldin(Wf,j,bf); return; } j-=HD;
    if (j < NL*NR*HD){ REL[j]=ldin(rel,j,bf); return; }
    return;
  }
  if ((int)blockIdx.x < PB+TB){
    int bid = ((int)blockIdx.x - PB)*4 + (threadIdx.x>>6);
    if (bid < NL*NR){
      int l = bid/NR, r = bid%NR;
      float x = ldin(rel,(size_t)(l*NR+r)*HD + lane,bf);
      float acc = 0.f;
      #pragma unroll
      for (int h=0; h<HD; ++h)
        acc = fmaf(bcastf(x, h), ldin(Wr,(size_t)(l*HD+h)*HD + lane,bf), acc);
      R2[(size_t)bid*HD + lane] = acc;
    } else if (bid < NL*NR + NL*B){
      int b2 = bid - NL*NR;
      int l = b2/B, b = b2%B;
      int r = q_rel[b];
      float x = ldin(rel,(size_t)(l*NR+r)*HD + lane,bf);
      float acc = ldin(bqr,(size_t)l*HD + lane,bf);
      #pragma unroll
      for (int h=0; h<HD; ++h)
        acc = fmaf(bcastf(x, h), ldin(Wqr,(size_t)(l*HD+h)*HD + lane,bf), acc);
      QR[(size_t)b2*HD + lane] = acc;
    }
    return;
  }
  int b = ((int)blockIdx.x - PB - TB)*4 + (threadIdx.x>>6);
  if (b >= B) return;
  int n = qsub[b];
  for (int b2 = b+1; b2 < B; ++b2) if (qsub[b2] == n) return;  // last dup wins
  int r = q_rel[b];
  float v = ldin(qre,(size_t)r*HD + lane,bf);
  hid[(size_t)n*HD + lane] = v;
  float acc = 0.f;
  #pragma unroll 8
  for (int h=0; h<HD; ++h)
    acc = fmaf(bcastf(v,h), ldin(Ws,(size_t)h*HD + lane,bf), acc);  // Ws layer 0 raw [h][a]
  HS2[(size_t)n*HD + lane] = acc;
  if (lane==0){
    atomicOr(&liveW[n>>5], 1u<<(n&31));
    stamp[n] = 1;
    int idx = atomicAdd(pcnt, 1);
    plist[idx] = n;
  }
}

// -------- fused edge phase: int4 4-edge/lane scan with next-window prefetch;
//          12.5 KB L1-resident liveness bitmask; LDS-buffered touched appends --------
__global__ void __launch_bounds__(256) k_edge(
    const int* __restrict__ sub, const int* __restrict__ rel_i,
    const int* __restrict__ obj, const int* __restrict__ eb,
    const unsigned* __restrict__ liveW,
    const float* __restrict__ hid, const float* __restrict__ HS2,
    const float* __restrict__ R2l, const float* __restrict__ QRl,
    const float* __restrict__ RELl, const float* __restrict__ waFl,
    const float* __restrict__ baFl, float* __restrict__ agg,
    int* __restrict__ stamp, int* __restrict__ tlist, int* __restrict__ tcnt,
    int ep, int E)
{
  __shared__ int s_cnt;
  __shared__ int s_base;
  __shared__ int s_buf[TCAP];
  if (threadIdx.x == 0) s_cnt = 0;
  __syncthreads();

  int lane = threadIdx.x & 63;
  int wid = (blockIdx.x*256 + threadIdx.x) >> 6;
  int nw = gridDim.x*4;
  long long stride = (long long)nw*256;
  float wa = waFl[lane];
  float ba = baFl[0];

  long long base0 = (long long)wid*256;
  int4 s4 = make_int4(0,0,0,0);
  if (base0 + 256 <= E)
    s4 = *reinterpret_cast<const int4*>(&sub[base0 + 4*(long long)lane]);

  for (long long base = base0; base < E; base += stride){
    bool vec = (base + 256 <= E);
    long long nbase = base + stride;
    int4 s4n = make_int4(0,0,0,0);
    if (nbase < E && nbase + 256 <= E)
      s4n = *reinterpret_cast<const int4*>(&sub[nbase + 4*(long long)lane]);

    unsigned long long m[4];
    if (vec){
      m[0] = __ballot(testbit(liveW, s4.x));
      m[1] = __ballot(testbit(liveW, s4.y));
      m[2] = __ballot(testbit(liveW, s4.z));
      m[3] = __ballot(testbit(liveW, s4.w));
    } else {
      #pragma unroll
      for (int j=0;j<4;++j){
        long long e = base + 4*(long long)lane + j;
        bool lv = (e < E) && testbit(liveW, sub[e]);
        m[j] = __ballot(lv);
      }
    }
    #pragma unroll
    for (int j=0;j<4;++j){
      unsigned long long mask = m[j];
      while (mask){
        int bit = (int)__ffsll(mask) - 1;
        mask &= mask - 1;
        long long ee = base + 4*(long long)bit + j;
        int ss = sub[ee], r = rel_i[ee], o = obj[ee], b = eb[ee];  // wave-uniform
        float hs  = hid[(size_t)ss*HD + lane];
        float pre = HS2[(size_t)ss*HD + lane] + R2l[(size_t)r*HD + lane] + QRl[(size_t)b*HD + lane];
        pre = fmaxf(pre, 0.f);
        float alpha = sigf(wsum(pre*wa) + ba);
        unsafeAtomicAdd(&agg[(size_t)o*HD + lane], alpha * hs * RELl[(size_t)r*HD + lane]);
        if (lane==0){
          int old = atomicExch(&stamp[o], ep);
          if (old != ep){
            int li = atomicAdd(&s_cnt, 1);
            if (li < TCAP) s_buf[li] = o;
            else { int gi = atomicAdd(tcnt, 1); tlist[gi] = o; }
          }
        }
      }
    }
    s4 = s4n;
  }

  __syncthreads();
  int cnt = s_cnt; if (cnt > TCAP) cnt = TCAP;
  if (threadIdx.x == 0 && cnt > 0) s_base = atomicAdd(tcnt, cnt);
  __syncthreads();
  if (cnt > 0){
    int b0 = s_base;
    for (int i = threadIdx.x; i < cnt; i += 256) tlist[b0 + i] = s_buf[i];
  }
}

// -------- node phase: NB=8 nodes/wave, global weight loads; per-j Whh only if prev-live;
//          k_died folded into tail (round-13 form, bitmask liveness) --------
__global__ void __launch_bounds__(256) k_node(
    const int* __restrict__ tlist, const int* __restrict__ tcnt,
    float* __restrict__ agg, float* __restrict__ hid, float* __restrict__ HS2,
    unsigned* __restrict__ liveW,
    const float* __restrict__ WhFl,  // [H][H]
    const float* __restrict__ WiTl,  // [H][3H]
    const float* __restrict__ WhTl,  // [H][3H]
    const float* __restrict__ biFl, const float* __restrict__ bhFl,
    const float* __restrict__ WsFn,  // [H][H] (next layer)
    const float* __restrict__ WfF,
    const int* __restrict__ plist, const int* __restrict__ pcnt,
    const int* __restrict__ stamp,
    float* __restrict__ out, int N, int isFirst, int isLast, int ep)
{
  int cntv = tcnt[0]; if (cntv > N) cntv = N;
  int lane = threadIdx.x & 63;
  int wid = (blockIdx.x*256 + threadIdx.x) >> 6;
  int nw = gridDim.x*4;
  float bi0=biFl[lane], bi1=biFl[HD+lane], bi2=biFl[2*HD+lane];
  float bh0=bhFl[lane], bh1=bhFl[HD+lane], bh2=bhFl[2*HD+lane];
  float wfv = isLast ? WfF[lane] : 0.f;

  for (int i0 = wid*NB; i0 < cntv; i0 += nw*NB){
    int nd[NB]; bool val[NB]; bool wp[NB]; float av[NB];
    #pragma unroll
    for (int j=0;j<NB;++j){
      val[j] = (i0+j) < cntv;
      nd[j]  = tlist[val[j] ? (i0+j) : i0];
      wp[j]  = (!isFirst) && val[j] && testbit(liveW, nd[j]);  // read BEFORE overwrite
      av[j]  = val[j] ? agg[(size_t)nd[j]*HD + lane] : 0.f;
    }
    if (!isLast){
      #pragma unroll
      for (int j=0;j<NB;++j) if (val[j]) agg[(size_t)nd[j]*HD + lane] = 0.f;
    }

    // hm = relu(av @ W_h): one weight load feeds NB FMAs
    float hm[NB];
    #pragma unroll
    for (int j=0;j<NB;++j) hm[j] = 0.f;
    #pragma unroll 8
    for (int h=0; h<HD; ++h){
      float w = WhFl[h*HD + lane];
      #pragma unroll
      for (int j=0;j<NB;++j) hm[j] = fmaf(bcastf(av[j],h), w, hm[j]);
    }
    float mask[NB]; float h0v[NB];
    #pragma unroll
    for (int j=0;j<NB;++j){
      hm[j] = fmaxf(hm[j], 0.f);
      mask[j] = (__ballot(hm[j] != 0.f) != 0ull) ? 1.f : 0.f;
      h0v[j] = wp[j] ? hid[(size_t)nd[j]*HD + lane] : 0.f;    // wp wave-uniform
    }

    float gi0[NB], gi1[NB], gi2[NB], gh0[NB], gh1[NB], gh2[NB];
    #pragma unroll
    for (int j=0;j<NB;++j){ gi0[j]=bi0; gi1[j]=bi1; gi2[j]=bi2; gh0[j]=bh0; gh1[j]=bh1; gh2[j]=bh2; }
    #pragma unroll 4
    for (int h=0; h<HD; ++h){
      const float* __restrict__ wr = WiTl + (size_t)h*192;
      float w0 = wr[lane], w1 = wr[64+lane], w2 = wr[128+lane];
      #pragma unroll
      for (int j=0;j<NB;++j){
        float x = bcastf(hm[j],h);
        gi0[j] = fmaf(x, w0, gi0[j]);
        gi1[j] = fmaf(x, w1, gi1[j]);
        gi2[j] = fmaf(x, w2, gi2[j]);
      }
    }
    // Whh matvec only for prev-live nodes (wave-uniform branch per j)
    #pragma unroll
    for (int j=0;j<NB;++j){
      if (wp[j]){
        #pragma unroll 4
        for (int h=0; h<HD; ++h){
          const float* __restrict__ wr = WhTl + (size_t)h*192;
          float y = bcastf(h0v[j],h);
          gh0[j] = fmaf(y, wr[lane],     gh0[j]);
          gh1[j] = fmaf(y, wr[64+lane],  gh1[j]);
          gh2[j] = fmaf(y, wr[128+lane], gh2[j]);
        }
      }
    }

    float hn[NB];
    #pragma unroll
    for (int j=0;j<NB;++j){
      float r = sigf(gi0[j]+gh0[j]);
      float z = sigf(gi1[j]+gh1[j]);
      float nn = tanhf(gi2[j] + r*gh2[j]);
      hn[j] = ((1.f - z)*nn + z*h0v[j])*mask[j];
    }

    if (isLast){
      #pragma unroll
      for (int j=0;j<NB;++j){
        float sc = wsum(hn[j] * wfv);
        if (lane==0 && val[j]) out[nd[j]] = sc;
      }
      continue;
    }
    #pragma unroll
    for (int j=0;j<NB;++j){
      unsigned long long lv = __ballot(hn[j] != 0.f);
      if (val[j]){
        hid[(size_t)nd[j]*HD + lane] = hn[j];
        if (lane==0){
          unsigned bit = 1u << (nd[j]&31);
          if (lv) atomicOr (&liveW[nd[j]>>5],  bit);
          else    atomicAnd(&liveW[nd[j]>>5], ~bit);
        }
      }
    }

    // HS2 for next layer: hn @ Ws[l+1]
    float acc[NB];
    #pragma unroll
    for (int j=0;j<NB;++j) acc[j] = 0.f;
    #pragma unroll 8
    for (int h=0; h<HD; ++h){
      float w = WsFn[h*HD + lane];
      #pragma unroll
      for (int j=0;j<NB;++j) acc[j] = fmaf(bcastf(hn[j],h), w, acc[j]);
    }
    #pragma unroll
    for (int j=0;j<NB;++j) if (val[j]) HS2[(size_t)nd[j]*HD + lane] = acc[j];
  }

  // folded k_died: clear liveness of prev-live nodes that got no messages this layer
  if (!isLast){
    int pc = pcnt[0]; if (pc > N) pc = N;
    for (int i = blockIdx.x*256 + threadIdx.x; i < pc; i += gridDim.x*256){
      int n = plist[i];
      if (stamp[n] != ep) atomicAnd(&liveW[n>>5], ~(1u<<(n&31)));
    }
  }
}

extern "C" void kernel_launch(void* const* d_in, const int* in_sizes, int n_in,
                              void* d_out, int out_size, void* d_ws, size_t ws_size,
                              hipStream_t stream)
{
  const int* sub   = (const int*)d_in[0];
  const int* rel_i = (const int*)d_in[1];
  const int* obj   = (const int*)d_in[2];
  const int* eb    = (const int*)d_in[3];
  const int* q_rel = (const int*)d_in[4];
  const int* qsub  = (const int*)d_in[5];
  const void* rela = d_in[6];
  const void* qre  = d_in[7];
  const void* Wsp  = d_in[8];
  const void* Wr   = d_in[9];
  const void* Wqr  = d_in[10];
  const void* bqr  = d_in[11];
  const void* wal  = d_in[12];
  const void* bal  = d_in[13];
  const void* W_h  = d_in[14];
  const void* Wih  = d_in[15];
  const void* Whh  = d_in[16];
  const void* bih  = d_in[17];
  const void* bhh  = d_in[18];
  const void* Wf   = d_in[19];

  int E  = in_sizes[0];
  int B  = in_sizes[4];
  int NR = in_sizes[6]/(NL*HD);
  int N  = out_size;
  int NW = (N + 31) / 32;

  float* ws = (float*)d_ws;
  size_t o = 0;
  float* agg  = ws + o; o += (size_t)N*HD;     // ┐ ONE memset region:
  int*   stamp= (int*)(ws + o); o += N;        // │ agg + stamp + cnts + liveW
  int*   cnts = (int*)(ws + o); o += 16;       // │
  unsigned* liveW = (unsigned*)(ws + o); o += NW;  // ┘ 12.5 KB bitmask
  float* hid  = ws + o; o += (size_t)N*HD;
  float* HS2  = ws + o; o += (size_t)N*HD;
  float* R2   = ws + o; o += (size_t)NL*NR*HD;
  float* QR   = ws + o; o += (size_t)NL*B*HD;
  float* REL  = ws + o; o += (size_t)NL*NR*HD;
  float* WhF  = ws + o; o += NL*HD*HD;
  float* WsF  = ws + o; o += NL*HD*HD;
  float* WiT  = ws + o; o += NL*192*HD;
  float* WhT  = ws + o; o += NL*192*HD;
  float* biF  = ws + o; o += NL*192;
  float* bhF  = ws + o; o += NL*192;
  float* waF  = ws + o; o += NL*HD;
  float* baF  = ws + o; o += NL;
  float* WfF  = ws + o; o += HD;
  int*   listA= (int*)(ws + o); o += N;
  int*   listB= (int*)(ws + o); o += N;

  // cnts: [3]=init live cnt, [4..6]=touched cnts
  size_t z1 = (size_t)N*HD*sizeof(float) + (size_t)N*sizeof(int)
            + 16*sizeof(int) + (size_t)NW*sizeof(unsigned);
  hipMemsetAsync(agg, 0, z1, stream);
  hipMemsetAsync(d_out, 0, (size_t)N*sizeof(float), stream);

  int prepN = 2*(NL*HD*HD) + 2*(NL*192*HD) + 2*(NL*192) + NL*HD + NL + HD + NL*NR*HD;
  int PB = (prepN + 255)/256;
  int TB = (NL*NR + NL*B + 3)/4;
  int IB = (B + 3)/4;
  k_setup<<<PB + TB + IB, 256, 0, stream>>>(
      W_h, Wsp, Wih, Whh, bih, bhh, wal, bal, Wf, rela, Wr, Wqr, bqr, qre,
      q_rel, qsub,
      WhF, WsF, WiT, WhT, biF, bhF, waF, baF, WfF, REL, R2, QR,
      hid, HS2, liveW, stamp, listA, cnts+3, NR, B, PB, TB);

  int* curT = listB;   // touched list this layer
  int* prevL = listA;  // live list entering this layer
  for (int l=0; l<NL; ++l){
    int ep = l + 2;
    k_edge<<<2048, 256, 0, stream>>>(sub, rel_i, obj, eb, liveW, hid, HS2,
        R2 + (size_t)l*NR*HD, QR + (size_t)l*B*HD, REL + (size_t)l*NR*HD,
        waF + l*HD, baF + l, agg, stamp, curT, cnts+4+l, ep, E);
    k_node<<<2048, 256, 0, stream>>>(curT, cnts+4+l, agg, hid, HS2, liveW,
        WhF + (size_t)l*HD*HD, WiT + (size_t)l*192*HD, WhT + (size_t)l*192*HD,
        biF + l*192, bhF + l*192,
        (l < NL-1) ? (WsF + (size_t)(l+1)*HD*HD) : WsF,
        WfF,
        prevL, (l==0) ? (cnts+3) : (cnts+4+l-1), stamp,
        (float*)d_out, N, (l==0)?1:0, (l==NL-1)?1:0, ep);
    int* t = prevL; prevL = curT; curT = t;
  }
}